// Round 2
// baseline (449.241 us; speedup 1.0000x reference)
//
#include <hip/hip_runtime.h>

#define B_PAIRS 2048
#define NSTRIDE 344   // 44 ligand + 300 protein rows per pair
#define LIG 44
#define FIN 128
#define N0 256
#define N1 128
#define N2 64
#define PAIRS_PER_BLK 8

// Generic register-tiled MLP layer over LDS activations.
// hin: LDS [8][KDIM], hout: LDS [8][NCOL], W: global row-major (KDIM, NCOL).
// Thread t owns PAIRS_PT pairs x COLS_PT cols; requires
// (NCOL/COLS_PT) * (8/PAIRS_PT) == 256.
template<int KDIM, int NCOL, int PAIRS_PT, int COLS_PT>
__device__ __forceinline__ void mlp_layer(
    const float* __restrict__ W, const float* __restrict__ b,
    const float* __restrict__ hin, float* __restrict__ hout,
    int t, bool do_relu)
{
    constexpr int CGROUPS = NCOL / COLS_PT;
    const int cg = t % CGROUPS;
    const int pg = t / CGROUPS;          // wave-uniform for our configs
    const int c0 = cg * COLS_PT;
    const int p0 = pg * PAIRS_PT;

    float acc[PAIRS_PT][COLS_PT];
    #pragma unroll
    for (int p = 0; p < PAIRS_PT; ++p)
        #pragma unroll
        for (int c = 0; c < COLS_PT; ++c)
            acc[p][c] = b[c0 + c];

    #pragma unroll 2
    for (int k = 0; k < KDIM; k += 4) {
        float4 xv[PAIRS_PT];
        #pragma unroll
        for (int p = 0; p < PAIRS_PT; ++p)
            xv[p] = *(const float4*)(hin + (p0 + p) * KDIM + k);  // LDS broadcast b128

        #pragma unroll
        for (int kk = 0; kk < 4; ++kk) {
            float wv[COLS_PT];
            if constexpr (COLS_PT == 2) {
                const float2 w2 = *(const float2*)(W + (size_t)(k + kk) * NCOL + c0);
                wv[0] = w2.x; wv[1] = w2.y;
            } else {
                wv[0] = W[(size_t)(k + kk) * NCOL + c0];
            }
            #pragma unroll
            for (int p = 0; p < PAIRS_PT; ++p) {
                const float xk = (kk == 0) ? xv[p].x
                               : (kk == 1) ? xv[p].y
                               : (kk == 2) ? xv[p].z : xv[p].w;
                #pragma unroll
                for (int c = 0; c < COLS_PT; ++c)
                    acc[p][c] += xk * wv[c];
            }
        }
    }

    #pragma unroll
    for (int p = 0; p < PAIRS_PT; ++p) {
        if constexpr (COLS_PT == 2) {
            float2 o;
            o.x = do_relu ? fmaxf(acc[p][0], 0.f) : acc[p][0];
            o.y = do_relu ? fmaxf(acc[p][1], 0.f) : acc[p][1];
            *(float2*)(hout + (p0 + p) * NCOL + c0) = o;
        } else {
            hout[(p0 + p) * NCOL + c0] = do_relu ? fmaxf(acc[p][0], 0.f) : acc[p][0];
        }
    }
}

__global__ __launch_bounds__(256) void fused_fcnn_kernel(
    const float* __restrict__ feat,
    const float* __restrict__ W0, const float* __restrict__ b0,
    const float* __restrict__ W1, const float* __restrict__ b1,
    const float* __restrict__ W2, const float* __restrict__ b2,
    const float* __restrict__ Wout, const float* __restrict__ bout,
    float* __restrict__ out)
{
    __shared__ float xs[PAIRS_PER_BLK * FIN];  // 4 KB
    __shared__ float h0[PAIRS_PER_BLK * N0];   // 8 KB
    __shared__ float h1[PAIRS_PER_BLK * N1];   // 4 KB
    __shared__ float h2[PAIRS_PER_BLK * N2];   // 2 KB

    const int t    = threadIdx.x;
    const int blk  = blockIdx.x;
    const int wave = t >> 6;
    const int lane = t & 63;
    const int joff = lane >> 5;   // which of 2 rows this half-wave covers
    const int fq   = lane & 31;   // float4 group within the 128-feature row

    // ---- Phase A: ligand segment sums; wave w handles pairs 2w, 2w+1 ----
    #pragma unroll
    for (int pp = 0; pp < 2; ++pp) {
        const int p = wave * 2 + pp;
        const float* base = feat + (size_t)(blk * PAIRS_PER_BLK + p) * NSTRIDE * FIN;
        float a0 = 0.f, a1 = 0.f, a2 = 0.f, a3 = 0.f;
        #pragma unroll
        for (int it = 0; it < LIG / 2; ++it) {   // 22 iters x 2 rows = 44
            const int j = it * 2 + joff;
            const float4 v = *(const float4*)(base + j * FIN + fq * 4);
            a0 += v.x; a1 += v.y; a2 += v.z; a3 += v.w;
        }
        a0 += __shfl_xor(a0, 32, 64);
        a1 += __shfl_xor(a1, 32, 64);
        a2 += __shfl_xor(a2, 32, 64);
        a3 += __shfl_xor(a3, 32, 64);
        if (lane < 32)
            *(float4*)(xs + p * FIN + fq * 4) = make_float4(a0, a1, a2, a3);
    }
    __syncthreads();

    // ---- Layer 0: 128 -> 256 (tile 4 pairs x 2 cols) ----
    mlp_layer<FIN, N0, 4, 2>(W0, b0, xs, h0, t, true);
    __syncthreads();

    // ---- Layer 1: 256 -> 128 (tile 2 pairs x 2 cols) ----
    mlp_layer<N0, N1, 2, 2>(W1, b1, h0, h1, t, true);
    __syncthreads();

    // ---- Layer 2: 128 -> 64 (tile 2 pairs x 1 col) ----
    mlp_layer<N1, N2, 2, 1>(W2, b2, h1, h2, t, true);
    __syncthreads();

    // ---- Output layer: 64 -> 1, shuffle-reduce over 32-lane halves ----
    {
        const int p = t >> 5;     // pair 0..7
        const int g = t & 31;
        const float* hr = h2 + p * N2;
        float v = hr[g] * Wout[g] + hr[g + 32] * Wout[g + 32];
        #pragma unroll
        for (int off = 16; off >= 1; off >>= 1)
            v += __shfl_xor(v, off, 64);
        if (g == 0)
            out[blk * PAIRS_PER_BLK + p] = v + bout[0];
    }
}

extern "C" void kernel_launch(void* const* d_in, const int* in_sizes, int n_in,
                              void* d_out, int out_size, void* d_ws, size_t ws_size,
                              hipStream_t stream) {
    // d_in order: batch_num_nodes, features, W0, b0, W1, b1, W2, b2, Wout, bout
    const float* feat = (const float*)d_in[1];
    const float* W0   = (const float*)d_in[2];
    const float* b0   = (const float*)d_in[3];
    const float* W1   = (const float*)d_in[4];
    const float* b1   = (const float*)d_in[5];
    const float* W2   = (const float*)d_in[6];
    const float* b2   = (const float*)d_in[7];
    const float* Wout = (const float*)d_in[8];
    const float* bout = (const float*)d_in[9];

    fused_fcnn_kernel<<<B_PAIRS / PAIRS_PER_BLK, 256, 0, stream>>>(
        feat, W0, b0, W1, b1, W2, b2, Wout, bout, (float*)d_out);
}

// Round 3
// 446.492 us; speedup vs baseline: 1.0062x; 1.0062x over previous
//
#include <hip/hip_runtime.h>

#define B_PAIRS 2048
#define NSTRIDE 344   // 44 ligand + 300 protein rows per pair
#define LIG 44
#define FIN 128
#define N0 256
#define N1 128
#define N2 64
#define PPB 4         // pairs per block -> 512 blocks, 2 blocks/CU, 8 waves/CU

// Register-tiled MLP layer over LDS activations.
// hin: LDS [NPAIRS][KDIM], hout: LDS [NPAIRS][NCOL], W: global row-major (KDIM,NCOL).
// Thread t owns PAIRS_PT pairs x COLS_PT cols.
template<int KDIM, int NCOL, int NPAIRS, int PAIRS_PT, int COLS_PT>
__device__ __forceinline__ void mlp_layer(
    const float* __restrict__ W, const float* __restrict__ b,
    const float* __restrict__ hin, float* __restrict__ hout,
    int t, bool do_relu)
{
    constexpr int CGROUPS = NCOL / COLS_PT;
    static_assert(CGROUPS * (NPAIRS / PAIRS_PT) == 256, "tiling must cover 256 threads");
    const int cg = t % CGROUPS;
    const int pg = t / CGROUPS;          // wave-uniform for all three configs
    const int c0 = cg * COLS_PT;
    const int p0 = pg * PAIRS_PT;

    float acc[PAIRS_PT][COLS_PT];
    #pragma unroll
    for (int p = 0; p < PAIRS_PT; ++p)
        #pragma unroll
        for (int c = 0; c < COLS_PT; ++c)
            acc[p][c] = b[c0 + c];

    #pragma unroll 2
    for (int k = 0; k < KDIM; k += 4) {
        float4 xv[PAIRS_PT];
        #pragma unroll
        for (int p = 0; p < PAIRS_PT; ++p)
            xv[p] = *(const float4*)(hin + (p0 + p) * KDIM + k);  // LDS broadcast b128

        #pragma unroll
        for (int kk = 0; kk < 4; ++kk) {
            float wv[COLS_PT];
            if constexpr (COLS_PT == 2) {
                const float2 w2 = *(const float2*)(W + (size_t)(k + kk) * NCOL + c0);
                wv[0] = w2.x; wv[1] = w2.y;
            } else {
                wv[0] = W[(size_t)(k + kk) * NCOL + c0];
            }
            #pragma unroll
            for (int p = 0; p < PAIRS_PT; ++p) {
                const float xk = (kk == 0) ? xv[p].x
                               : (kk == 1) ? xv[p].y
                               : (kk == 2) ? xv[p].z : xv[p].w;
                #pragma unroll
                for (int c = 0; c < COLS_PT; ++c)
                    acc[p][c] += xk * wv[c];
            }
        }
    }

    #pragma unroll
    for (int p = 0; p < PAIRS_PT; ++p) {
        if constexpr (COLS_PT == 2) {
            float2 o;
            o.x = do_relu ? fmaxf(acc[p][0], 0.f) : acc[p][0];
            o.y = do_relu ? fmaxf(acc[p][1], 0.f) : acc[p][1];
            *(float2*)(hout + (p0 + p) * NCOL + c0) = o;
        } else {
            hout[(p0 + p) * NCOL + c0] = do_relu ? fmaxf(acc[p][0], 0.f) : acc[p][0];
        }
    }
}

__global__ __launch_bounds__(256) void fused_fcnn_kernel(
    const float* __restrict__ feat,
    const float* __restrict__ W0, const float* __restrict__ b0,
    const float* __restrict__ W1, const float* __restrict__ b1,
    const float* __restrict__ W2, const float* __restrict__ b2,
    const float* __restrict__ Wout, const float* __restrict__ bout,
    float* __restrict__ out)
{
    __shared__ float xs[PPB * FIN];  // 2 KB
    __shared__ float h0[PPB * N0];   // 4 KB
    __shared__ float h1[PPB * N1];   // 2 KB
    __shared__ float h2[PPB * N2];   // 1 KB

    const int t    = threadIdx.x;
    const int blk  = blockIdx.x;
    const int wave = t >> 6;
    const int lane = t & 63;
    const int joff = lane >> 5;   // which of 2 rows this half-wave covers
    const int fq   = lane & 31;   // float4 group within the 128-feature row

    // ---- Phase A: ligand segment sum; wave w handles pair w of this block ----
    {
        const float* base = feat + (size_t)(blk * PPB + wave) * NSTRIDE * FIN;
        float a0 = 0.f, a1 = 0.f, a2 = 0.f, a3 = 0.f;
        #pragma unroll
        for (int it = 0; it < LIG / 2; ++it) {   // 22 iters x 2 rows = 44
            const int j = it * 2 + joff;
            const float4 v = *(const float4*)(base + j * FIN + fq * 4);
            a0 += v.x; a1 += v.y; a2 += v.z; a3 += v.w;
        }
        a0 += __shfl_xor(a0, 32, 64);
        a1 += __shfl_xor(a1, 32, 64);
        a2 += __shfl_xor(a2, 32, 64);
        a3 += __shfl_xor(a3, 32, 64);
        if (lane < 32)
            *(float4*)(xs + wave * FIN + fq * 4) = make_float4(a0, a1, a2, a3);
    }
    __syncthreads();

    // ---- Layer 0: 128 -> 256 (2 pairs x 2 cols per thread) ----
    mlp_layer<FIN, N0, PPB, 2, 2>(W0, b0, xs, h0, t, true);
    __syncthreads();

    // ---- Layer 1: 256 -> 128 (1 pair x 2 cols per thread) ----
    mlp_layer<N0, N1, PPB, 1, 2>(W1, b1, h0, h1, t, true);
    __syncthreads();

    // ---- Layer 2: 128 -> 64 (1 pair x 1 col per thread) ----
    mlp_layer<N1, N2, PPB, 1, 1>(W2, b2, h1, h2, t, true);
    __syncthreads();

    // ---- Output layer: 64 -> 1; wave w reduces pair w ----
    {
        float v = h2[wave * N2 + lane] * Wout[lane];
        #pragma unroll
        for (int off = 32; off >= 1; off >>= 1)
            v += __shfl_xor(v, off, 64);
        if (lane == 0)
            out[blk * PPB + wave] = v + bout[0];
    }
}

extern "C" void kernel_launch(void* const* d_in, const int* in_sizes, int n_in,
                              void* d_out, int out_size, void* d_ws, size_t ws_size,
                              hipStream_t stream) {
    // d_in order: batch_num_nodes, features, W0, b0, W1, b1, W2, b2, Wout, bout
    const float* feat = (const float*)d_in[1];
    const float* W0   = (const float*)d_in[2];
    const float* b0   = (const float*)d_in[3];
    const float* W1   = (const float*)d_in[4];
    const float* b1   = (const float*)d_in[5];
    const float* W2   = (const float*)d_in[6];
    const float* b2   = (const float*)d_in[7];
    const float* Wout = (const float*)d_in[8];
    const float* bout = (const float*)d_in[9];

    fused_fcnn_kernel<<<B_PAIRS / PPB, 256, 0, stream>>>(
        feat, W0, b0, W1, b1, W2, b2, Wout, bout, (float*)d_out);
}